// Round 6
// baseline (12860.265 us; speedup 1.0000x reference)
//
#include <hip/hip_runtime.h>
#include <math.h>

#define BATCH 256
#define TT    784
#define HH    512
#define NCLS  10

#define NB 64          // batch groups
#define NJ 4           // blocks per group; block owns 128 cols
#define MB 4           // batch rows per group
#define HJ 128         // output cols per block
#define NT 1024        // threads per block (16 waves, 4/SIMD)

typedef unsigned long long ull;
typedef unsigned int uint32;

#define AL(p)    __hip_atomic_load((p), __ATOMIC_RELAXED, __HIP_MEMORY_SCOPE_AGENT)
#define AS(p, v) __hip_atomic_store((p), (v), __ATOMIC_RELAXED, __HIP_MEMORY_SCOPE_AGENT)

// R0-R5 LESSON (the VGPR-budget mechanism): the backend's register budget is
// VGPR-file / achievable-occupancy, where achievable occupancy includes the
// LDS bound. At <=80 KB LDS, 2 blocks/CU are deemed schedulable -> 4
// waves/EU -> hard budget 128 VGPR. Every 512-thread variant (128 weight
// floats/thread) landed <=128 and spilled the weights; no attribute/pin/
// sched_barrier could override it. THIS version fits the design INSIDE the
// 128 budget instead: 1024 threads/block, 64 weight floats (16 float4) per
// thread; peak demand ~64w+16acc+16h+~25misc ~= 121 <= 128. LDS grows to
// 87 KB (1 block/CU naturally) and 4 waves/SIMD double latency hiding for
// the exchange phases.
//
// d_ws layout:
//   [0, 4096)   : wflags uint32[NB][16] — flag[bb][g*4+r] >= t  <=>  producer
//                 g's row r of h_t is visible (stored + producer vmcnt drained).
//   [8192, ...) : double-buffered h state (2 * B * H f32, agent relaxed).

__global__ __launch_bounds__(256) void rnn_init_kernel(uint32* wflags) {
    const int i = blockIdx.x * blockDim.x + threadIdx.x;
    if (i < NB * 16) AS(&wflags[i], 0u);
}

// Opaque register pin: weights become outputs of a volatile asm — cannot be
// rematerialized or sunk into the loop.
#define PIN(V) asm volatile("" : "+v"((V).x), "+v"((V).y), "+v"((V).z), "+v"((V).w))

__global__ __launch_bounds__(NT)
__attribute__((amdgpu_waves_per_eu(4, 4)))
void rnn_main_kernel(
    const float* __restrict__ inputs, const int* __restrict__ order,
    const float* __restrict__ W_ih, const float* __restrict__ b_ih,
    const float* __restrict__ W_hh, const float* __restrict__ b_hh,
    float* __restrict__ hbuf, uint32* __restrict__ wflags)
{
    __shared__ float hp[MB * HH];            // 8 KB : h tile (canonical col layout)
    __shared__ float pbuf[32 * MB * HJ];     // 64 KB: partials [kg][row][pack j]
    __shared__ float xall[TT * MB];          // 12.25 KB: inputs[b][order[t]]
    __shared__ float wih_s[HJ];
    __shared__ float bias_s[HJ];
    // total ~87.3 KB -> exactly 1 block/CU -> 4 waves/EU -> budget 128 VGPR

    const int tid   = threadIdx.x;
    const int blk   = blockIdx.x;
    const int bb    = blk & (NB - 1);        // group; members blk=bb+64g -> same XCD under %8
    const int jjg   = blk >> 6;              // producer id 0..3: cols [jjg*128, +128)
    const int jbase = jjg * HJ;
    const int bbase = bb * MB;
    const int j   = tid & 31;                // base col lane: cols {j, j+32, j+64, j+96}
    const int kg  = tid >> 5;                // k-chunk 0..31 (16 k each)
    const int w   = tid >> 6;                // wave 0..15: k-window [32w,+32)
    const int g   = w >> 2;                  // producer of this wave's k-window
    const int l   = tid & 63;
    const int r4  = l >> 4;                  // staging: batch row 0..3
    const int c4  = l & 15;                  // staging: 8B chunk within 32-col window

    // ---- W_hh slice in registers: 4 cols x 16 k = 16 float4 (64 VGPR)
    const float4* wpa = (const float4*)(W_hh + (size_t)(jbase + j +  0) * HH + kg * 16);
    const float4* wpb = (const float4*)(W_hh + (size_t)(jbase + j + 32) * HH + kg * 16);
    const float4* wpc = (const float4*)(W_hh + (size_t)(jbase + j + 64) * HH + kg * 16);
    const float4* wpd = (const float4*)(W_hh + (size_t)(jbase + j + 96) * HH + kg * 16);
    float4 wa0 = wpa[0], wa1 = wpa[1], wa2 = wpa[2], wa3 = wpa[3];
    float4 wb0 = wpb[0], wb1 = wpb[1], wb2 = wpb[2], wb3 = wpb[3];
    float4 wc0 = wpc[0], wc1 = wpc[1], wc2 = wpc[2], wc3 = wpc[3];
    float4 wd0 = wpd[0], wd1 = wpd[1], wd2 = wpd[2], wd3 = wpd[3];

    PIN(wa0); PIN(wa1); PIN(wa2); PIN(wa3);
    PIN(wb0); PIN(wb1); PIN(wb2); PIN(wb3);
    PIN(wc0); PIN(wc1); PIN(wc2); PIN(wc3);
    PIN(wd0); PIN(wd1); PIN(wd2); PIN(wd3);

    if (tid < HJ) {
        wih_s[tid]  = W_ih[jbase + tid];
        bias_s[tid] = b_ih[jbase + tid] + b_hh[jbase + tid];
    }
    for (int idx = tid; idx < TT * MB; idx += NT) {
        const int t = idx >> 2;
        const int b = idx & (MB - 1);
        xall[idx] = inputs[(size_t)(bbase + b) * TT + order[t]];
    }
    if (tid < 512) ((float4*)hp)[tid] = make_float4(0.f, 0.f, 0.f, 0.f); // h_0 = 0
    __syncthreads();

    const float4* hp4 = (const float4*)hp;
    float4* P4 = (float4*)pbuf;

    for (int t = 0; t < TT; ++t) {
        const int p = t & 1;

        // ---- per-wave gate + stage: poll producer g's 4 row-flags (one line),
        //      then load this wave's 512 B slice (4 rows x 32 cols)
        if (t > 0 && g != jjg) {
            const uint32 tg = (uint32)t;
            const ull* f8 = (const ull*)(wflags + bb * 16 + g * 4);
            for (;;) {
                const ull f0 = AL(f8), f1 = AL(f8 + 1);
                if ((uint32)f0 >= tg && (uint32)(f0 >> 32) >= tg &&
                    (uint32)f1 >= tg && (uint32)(f1 >> 32) >= tg) break;
            }
            const ull* src = (const ull*)(hbuf + (size_t)p * BATCH * HH
                                          + (size_t)(bbase + r4) * HH + w * 32 + c4 * 2);
            const ull u0 = AL(src);
            ull* hpu = (ull*)hp;
            const int di = (r4 * HH + w * 32 + c4 * 2) >> 1;
            hpu[di] = u0;
        }
        // intra-wave LDS RAW: compiler's lgkmcnt covers the hp reads below.

        // ---- partials: 4 rows x 4 cols, k-window 16
        float aa0=0.f,aa1=0.f,aa2=0.f,aa3=0.f;
        float ab0=0.f,ab1=0.f,ab2=0.f,ab3=0.f;
        float ac0=0.f,ac1=0.f,ac2=0.f,ac3=0.f;
        float ad0=0.f,ad1=0.f,ad2=0.f,ad3=0.f;

#define FMA4(ACC, WV, HV) \
        ACC = fmaf(WV.x, HV.x, ACC); ACC = fmaf(WV.y, HV.y, ACC); \
        ACC = fmaf(WV.z, HV.z, ACC); ACC = fmaf(WV.w, HV.w, ACC);
#define ROW(B) { \
        const float4* hr = hp4 + (B)*128 + kg*4; \
        const float4 h0=hr[0],h1=hr[1],h2=hr[2],h3=hr[3]; \
        FMA4(aa##B, wa0,h0) FMA4(aa##B, wa1,h1) FMA4(aa##B, wa2,h2) FMA4(aa##B, wa3,h3) \
        FMA4(ab##B, wb0,h0) FMA4(ab##B, wb1,h1) FMA4(ab##B, wb2,h2) FMA4(ab##B, wb3,h3) \
        FMA4(ac##B, wc0,h0) FMA4(ac##B, wc1,h1) FMA4(ac##B, wc2,h2) FMA4(ac##B, wc3,h3) \
        FMA4(ad##B, wd0,h0) FMA4(ad##B, wd1,h1) FMA4(ad##B, wd2,h2) FMA4(ad##B, wd3,h3) }

        // sched_barrier(0) between rows: cap the pressure peak at one row's
        // h-window (16 regs): 64 w + 16 h + 16 acc + ~25 misc ~= 121 <= 128.
        ROW(0) __builtin_amdgcn_sched_barrier(0);
        ROW(1) __builtin_amdgcn_sched_barrier(0);
        ROW(2) __builtin_amdgcn_sched_barrier(0);
        ROW(3) __builtin_amdgcn_sched_barrier(0);
#undef ROW
#undef FMA4

        // pack: P4[(kg*4+row)*32 + j] = cols {j, j+32, j+64, j+96}
        P4[(kg*4 + 0)*32 + j] = make_float4(aa0, ab0, ac0, ad0);
        P4[(kg*4 + 1)*32 + j] = make_float4(aa1, ab1, ac1, ad1);
        P4[(kg*4 + 2)*32 + j] = make_float4(aa2, ab2, ac2, ad2);
        P4[(kg*4 + 3)*32 + j] = make_float4(aa3, ab3, ac3, ad3);
        __syncthreads();                 // B: all partials ready

        // ---- reduce: wave r (r<4) handles row r, lanes<32; publish per row
        if (w < MB && l < 32) {
            const int rr = w;
            float4 s = P4[rr * 32 + j];
            #pragma unroll
            for (int kk = 1; kk < 32; ++kk) {
                const float4 v = P4[(kk*4 + rr)*32 + j];
                s.x += v.x; s.y += v.y; s.z += v.z; s.w += v.w;
            }
            const float xv = xall[t * MB + rr];
            s.x = tanhf(s.x + xv * wih_s[j +  0] + bias_s[j +  0]);
            s.y = tanhf(s.y + xv * wih_s[j + 32] + bias_s[j + 32]);
            s.z = tanhf(s.z + xv * wih_s[j + 64] + bias_s[j + 64]);
            s.w = tanhf(s.w + xv * wih_s[j + 96] + bias_s[j + 96]);
            float* drow = hbuf + (size_t)(p ^ 1) * BATCH * HH
                               + (size_t)(bbase + rr) * HH + jbase;
            AS(&drow[j +  0], s.x);
            AS(&drow[j + 32], s.y);
            AS(&drow[j + 64], s.z);
            AS(&drow[j + 96], s.w);
            // own-slice shortcut: waves [4*jjg, 4*jjg+4) skip staging next step
            hp[rr * HH + jbase + j +  0] = s.x;
            hp[rr * HH + jbase + j + 32] = s.y;
            hp[rr * HH + jbase + j + 64] = s.z;
            hp[rr * HH + jbase + j + 96] = s.w;
            // drain THIS wave's stores, then publish row flag
            asm volatile("s_waitcnt vmcnt(0)" ::: "memory");
            if (l == 0) AS(&wflags[bb * 16 + jjg * 4 + rr], (uint32)(t + 1));
        }
        __syncthreads();                 // C: pbuf WAR + own-slice visible
    }
}

__global__ __launch_bounds__(256) void rnn_tail_kernel(
    const float* __restrict__ hfin,   // final h in buf 0 (TT even)
    const float* __restrict__ lin_W, const float* __restrict__ lin_b,
    const int* __restrict__ y, float* __restrict__ out)
{
    __shared__ float redf[256];
    __shared__ int   redi[256];
    const int b = threadIdx.x;
    const float* hrow = hfin + (size_t)b * HH;

    float logits[NCLS];
    #pragma unroll
    for (int c = 0; c < NCLS; ++c) {
        float s = lin_b[c];
        const float* wrow = lin_W + (size_t)c * HH;
        for (int k = 0; k < HH; k += 4) {
            float4 hv = *(const float4*)(hrow + k);
            float4 wv = *(const float4*)(wrow + k);
            s += hv.x * wv.x + hv.y * wv.y + hv.z * wv.z + hv.w * wv.w;
        }
        logits[c] = s;
    }
    int am = 0; float m = logits[0];
    #pragma unroll
    for (int c = 1; c < NCLS; ++c) if (logits[c] > m) { m = logits[c]; am = c; } // first-max
    float sum = 0.0f;
    #pragma unroll
    for (int c = 0; c < NCLS; ++c) sum += expf(logits[c] - m);
    const float lse = m + logf(sum);
    const int yy = y[b];
    redf[b] = lse - logits[yy];
    redi[b] = (am == yy) ? 1 : 0;
    __syncthreads();
    for (int s2 = 128; s2 > 0; s2 >>= 1) {
        if (b < s2) { redf[b] += redf[b + s2]; redi[b] += redi[b + s2]; }
        __syncthreads();
    }
    if (b == 0) {
        out[0] = redf[0] / (float)BATCH;  // loss
        out[1] = (float)redi[0];          // correct count
    }
}

extern "C" void kernel_launch(void* const* d_in, const int* in_sizes, int n_in,
                              void* d_out, int out_size, void* d_ws, size_t ws_size,
                              hipStream_t stream) {
    const float* inputs = (const float*)d_in[0];
    const int*   y      = (const int*)  d_in[1];
    const int*   order  = (const int*)  d_in[2];
    const float* W_ih   = (const float*)d_in[3];
    const float* b_ih   = (const float*)d_in[4];
    const float* W_hh   = (const float*)d_in[5];
    const float* b_hh   = (const float*)d_in[6];
    const float* lin_W  = (const float*)d_in[7];
    const float* lin_b  = (const float*)d_in[8];
    float* out = (float*)d_out;

    uint32* wflags = (uint32*)d_ws;
    float*  hbuf   = (float*)((char*)d_ws + 8192);

    hipLaunchKernelGGL(rnn_init_kernel, dim3(4), dim3(256), 0, stream, wflags);

    void* args[] = {(void*)&inputs, (void*)&order, (void*)&W_ih, (void*)&b_ih,
                    (void*)&W_hh, (void*)&b_hh, (void*)&hbuf, (void*)&wflags};
    hipError_t err = hipLaunchCooperativeKernel((void*)rnn_main_kernel,
                                                dim3(NB * NJ), dim3(NT), args, 0, stream);
    if (err != hipSuccess) {
        hipLaunchKernelGGL(rnn_main_kernel, dim3(NB * NJ), dim3(NT), 0, stream,
                           inputs, order, W_ih, b_ih, W_hh, b_hh, hbuf, wflags);
    }

    hipLaunchKernelGGL(rnn_tail_kernel, dim3(1), dim3(256), 0, stream,
                       hbuf, lin_W, lin_b, y, out);
}

// Round 7
// 4566.541 us; speedup vs baseline: 2.8162x; 2.8162x over previous
//
#include <hip/hip_runtime.h>
#include <math.h>

#define BATCH 256
#define TT    784
#define HH    512
#define NCLS  10

#define NB 64          // batch groups
#define NJ 4           // blocks per group; block owns 128 cols
#define MB 4           // batch rows per group
#define HJ 128         // output cols per block
#define NT 512         // threads per block (8 waves, 2/SIMD)

typedef unsigned long long ull;
typedef unsigned int uint32;

#define AL(p)    __hip_atomic_load((p), __ATOMIC_RELAXED, __HIP_MEMORY_SCOPE_AGENT)
#define AS(p, v) __hip_atomic_store((p), (v), __ATOMIC_RELAXED, __HIP_MEMORY_SCOPE_AGENT)

// R0-R6 LESSONS:
//  * VGPR budget = file / achievable-occupancy; LDS <= 80 KB => 2 blocks/CU
//    deemed schedulable => 4 waves/EU => budget 128 => the 128 weight floats
//    spill/remat (landed 108/120/120/88/120 across variants).
//  * 1024-thr variant (R6): budget collapsed to 64, accumulators spilled to
//    scratch = 33.7 GB HBM traffic, 4x slower. Reverted.
//  * R5's dead-store LDS pad was DCE'd (LDS_Block_Size never moved) — the
//    >80 KB experiment never ran. THIS version makes the extra LDS real:
//    double-buffered pbuf (2 x 32 KB), total 85.25 KB => 1 block/CU =>
//    2 waves/EU => budget 256, and the parity-indexed pbuf lets us DELETE
//    barrier C (WAR on pbuf[p] at t+2 is covered by barrier B(t+1)).
//    All waves stage h from hbuf (no cross-wave LDS dependency remains;
//    flag protocol provides ordering: producer drains vmcnt before flag,
//    consumer polls flag before loading).
//
// d_ws layout:
//   [0, 4096)   : wflags uint32[NB][16] — flag[bb][g*4+r] >= t  <=>  producer
//                 g's row r of h_t is visible (stored + producer vmcnt drained).
//   [8192, ...) : double-buffered h state (2 * B * H f32, agent relaxed).

__global__ __launch_bounds__(256) void rnn_init_kernel(uint32* wflags) {
    const int i = blockIdx.x * blockDim.x + threadIdx.x;
    if (i < NB * 16) AS(&wflags[i], 0u);
}

// Opaque register pin: weights become outputs of a volatile asm — cannot be
// rematerialized or sunk into the loop.
#define PIN(V) asm volatile("" : "+v"((V).x), "+v"((V).y), "+v"((V).z), "+v"((V).w))

__global__ __launch_bounds__(NT)
__attribute__((amdgpu_waves_per_eu(2, 2)))
void rnn_main_kernel(
    const float* __restrict__ inputs, const int* __restrict__ order,
    const float* __restrict__ W_ih, const float* __restrict__ b_ih,
    const float* __restrict__ W_hh, const float* __restrict__ b_hh,
    float* __restrict__ hbuf, uint32* __restrict__ wflags)
{
    __shared__ float hp[MB * HH];              // 8 KB : h tile (per-wave windows)
    __shared__ float pbuf[2 * 16 * MB * HJ];   // 64 KB: DOUBLE-BUFFERED partials
    __shared__ float xall[TT * MB];            // 12.25 KB: inputs[b][order[t]]
    __shared__ float wih_s[HJ];
    __shared__ float bias_s[HJ];
    // total 85.25 KB -> 1 block/CU -> 2 waves/EU -> VGPR budget 256

    const int tid   = threadIdx.x;
    const int blk   = blockIdx.x;
    const int bb    = blk & (NB - 1);        // group; members blk=bb+64g -> same XCD under %8
    const int jjg   = blk >> 6;              // producer id 0..3: cols [jjg*128, +128)
    const int jbase = jjg * HJ;
    const int bbase = bb * MB;
    const int j   = tid & 31;                // base col lane: cols {j, j+32, j+64, j+96}
    const int kg  = tid >> 5;                // k-chunk 0..15 (32 k each)
    const int w   = tid >> 6;                // wave: k-window [64w,+64), producer g=w>>1
    const int g   = w >> 1;
    const int l   = tid & 63;
    const int r4  = l >> 4;                  // staging: batch row 0..3
    const int c4  = l & 15;                  // staging: 16B chunk within 64-col window

    // ---- W_hh slice in NAMED registers: 4 cols x 32 k = 32 float4 (128 VGPR)
    const float4* wpa = (const float4*)(W_hh + (size_t)(jbase + j +  0) * HH + kg * 32);
    const float4* wpb = (const float4*)(W_hh + (size_t)(jbase + j + 32) * HH + kg * 32);
    const float4* wpc = (const float4*)(W_hh + (size_t)(jbase + j + 64) * HH + kg * 32);
    const float4* wpd = (const float4*)(W_hh + (size_t)(jbase + j + 96) * HH + kg * 32);
    float4 wa0 = wpa[0], wa1 = wpa[1], wa2 = wpa[2], wa3 = wpa[3];
    float4 wa4 = wpa[4], wa5 = wpa[5], wa6 = wpa[6], wa7 = wpa[7];
    float4 wb0 = wpb[0], wb1 = wpb[1], wb2 = wpb[2], wb3 = wpb[3];
    float4 wb4 = wpb[4], wb5 = wpb[5], wb6 = wpb[6], wb7 = wpb[7];
    float4 wc0 = wpc[0], wc1 = wpc[1], wc2 = wpc[2], wc3 = wpc[3];
    float4 wc4 = wpc[4], wc5 = wpc[5], wc6 = wpc[6], wc7 = wpc[7];
    float4 wd0 = wpd[0], wd1 = wpd[1], wd2 = wpd[2], wd3 = wpd[3];
    float4 wd4 = wpd[4], wd5 = wpd[5], wd6 = wpd[6], wd7 = wpd[7];

    PIN(wa0); PIN(wa1); PIN(wa2); PIN(wa3);
    PIN(wa4); PIN(wa5); PIN(wa6); PIN(wa7);
    PIN(wb0); PIN(wb1); PIN(wb2); PIN(wb3);
    PIN(wb4); PIN(wb5); PIN(wb6); PIN(wb7);
    PIN(wc0); PIN(wc1); PIN(wc2); PIN(wc3);
    PIN(wc4); PIN(wc5); PIN(wc6); PIN(wc7);
    PIN(wd0); PIN(wd1); PIN(wd2); PIN(wd3);
    PIN(wd4); PIN(wd5); PIN(wd6); PIN(wd7);

    if (tid < HJ) {
        wih_s[tid]  = W_ih[jbase + tid];
        bias_s[tid] = b_ih[jbase + tid] + b_hh[jbase + tid];
    }
    for (int idx = tid; idx < TT * MB; idx += NT) {
        const int t = idx >> 2;
        const int b = idx & (MB - 1);
        xall[idx] = inputs[(size_t)(bbase + b) * TT + order[t]];
    }
    ((float4*)hp)[tid] = make_float4(0.f, 0.f, 0.f, 0.f);   // h_0 = 0 (8 KB)
    __syncthreads();

    const float4* hp4 = (const float4*)hp;
    float4* P4 = (float4*)pbuf;              // two 2048-float4 halves, parity p

    for (int t = 0; t < TT; ++t) {
        const int p = t & 1;
        float4* Pp = P4 + (p << 11);         // this step's pbuf half

        // ---- per-wave gate + stage: poll producer g's 4 row-flags (one line),
        //      then load this wave's 1 KB slice (ALL waves, incl. own-block:
        //      own rows are L2 hits; removes the cross-wave hp dependency)
        if (t > 0) {
            const uint32 tg = (uint32)t;
            const ull* f8 = (const ull*)(wflags + bb * 16 + g * 4);
            for (;;) {
                const ull f0 = AL(f8), f1 = AL(f8 + 1);
                if ((uint32)f0 >= tg && (uint32)(f0 >> 32) >= tg &&
                    (uint32)f1 >= tg && (uint32)(f1 >> 32) >= tg) break;
            }
            const ull* src = (const ull*)(hbuf + (size_t)p * BATCH * HH
                                          + (size_t)(bbase + r4) * HH + w * 64 + c4 * 4);
            const ull u0 = AL(src), u1 = AL(src + 1);
            ull* hpu = (ull*)hp;
            const int di = (r4 * HH + w * 64 + c4 * 4) >> 1;
            hpu[di] = u0; hpu[di + 1] = u1;
        }
        // hp hazards are now wave-private only (each wave reads exactly the
        // k-window it staged); compiler's lgkmcnt covers the RAW below.

        // ---- partials: 4 rows x 4 cols, k-window 32; h reads are 2-addr broadcasts
        float aa0=0.f,aa1=0.f,aa2=0.f,aa3=0.f;
        float ab0=0.f,ab1=0.f,ab2=0.f,ab3=0.f;
        float ac0=0.f,ac1=0.f,ac2=0.f,ac3=0.f;
        float ad0=0.f,ad1=0.f,ad2=0.f,ad3=0.f;

#define FMA4(ACC, WV, HV) \
        ACC = fmaf(WV.x, HV.x, ACC); ACC = fmaf(WV.y, HV.y, ACC); \
        ACC = fmaf(WV.z, HV.z, ACC); ACC = fmaf(WV.w, HV.w, ACC);
#define ROW(B) { \
        const float4* hr = hp4 + (B)*128 + kg*8; \
        const float4 h0=hr[0],h1=hr[1],h2=hr[2],h3=hr[3]; \
        const float4 h4=hr[4],h5=hr[5],h6=hr[6],h7=hr[7]; \
        FMA4(aa##B, wa0,h0) FMA4(aa##B, wa1,h1) FMA4(aa##B, wa2,h2) FMA4(aa##B, wa3,h3) \
        FMA4(aa##B, wa4,h4) FMA4(aa##B, wa5,h5) FMA4(aa##B, wa6,h6) FMA4(aa##B, wa7,h7) \
        FMA4(ab##B, wb0,h0) FMA4(ab##B, wb1,h1) FMA4(ab##B, wb2,h2) FMA4(ab##B, wb3,h3) \
        FMA4(ab##B, wb4,h4) FMA4(ab##B, wb5,h5) FMA4(ab##B, wb6,h6) FMA4(ab##B, wb7,h7) \
        FMA4(ac##B, wc0,h0) FMA4(ac##B, wc1,h1) FMA4(ac##B, wc2,h2) FMA4(ac##B, wc3,h3) \
        FMA4(ac##B, wc4,h4) FMA4(ac##B, wc5,h5) FMA4(ac##B, wc6,h6) FMA4(ac##B, wc7,h7) \
        FMA4(ad##B, wd0,h0) FMA4(ad##B, wd1,h1) FMA4(ad##B, wd2,h2) FMA4(ad##B, wd3,h3) \
        FMA4(ad##B, wd4,h4) FMA4(ad##B, wd5,h5) FMA4(ad##B, wd6,h6) FMA4(ad##B, wd7,h7) }

        // sched_barrier(0) between rows: cap the scheduler's pressure peak at
        // one row's h-window (32 regs): 128 w + 32 h + 16 acc + ~25 misc ~= 200 <= 256.
        ROW(0) __builtin_amdgcn_sched_barrier(0);
        ROW(1) __builtin_amdgcn_sched_barrier(0);
        ROW(2) __builtin_amdgcn_sched_barrier(0);
        ROW(3) __builtin_amdgcn_sched_barrier(0);
#undef ROW
#undef FMA4

        // pack: Pp[(kg*4+row)*32 + j] = cols {j, j+32, j+64, j+96}
        Pp[(kg*4 + 0)*32 + j] = make_float4(aa0, ab0, ac0, ad0);
        Pp[(kg*4 + 1)*32 + j] = make_float4(aa1, ab1, ac1, ad1);
        Pp[(kg*4 + 2)*32 + j] = make_float4(aa2, ab2, ac2, ad2);
        Pp[(kg*4 + 3)*32 + j] = make_float4(aa3, ab3, ac3, ad3);
        __syncthreads();                 // B: all partials ready
        // (no barrier C: pbuf[p] is re-written only at t+2, and any wave
        //  reaching pack(t+2) has passed B(t+1), which is after reduce(t).)

        // ---- reduce: wave r (r<4) handles row r, lanes<32; publish per row
        if (w < MB && l < 32) {
            const int rr = w;
            float4 s = Pp[rr * 32 + j];
            #pragma unroll
            for (int kk = 1; kk < 16; ++kk) {
                const float4 v = Pp[(kk*4 + rr)*32 + j];
                s.x += v.x; s.y += v.y; s.z += v.z; s.w += v.w;
            }
            const float xv = xall[t * MB + rr];
            s.x = tanhf(s.x + xv * wih_s[j +  0] + bias_s[j +  0]);
            s.y = tanhf(s.y + xv * wih_s[j + 32] + bias_s[j + 32]);
            s.z = tanhf(s.z + xv * wih_s[j + 64] + bias_s[j + 64]);
            s.w = tanhf(s.w + xv * wih_s[j + 96] + bias_s[j + 96]);
            float* drow = hbuf + (size_t)(p ^ 1) * BATCH * HH
                               + (size_t)(bbase + rr) * HH + jbase;
            AS(&drow[j +  0], s.x);
            AS(&drow[j + 32], s.y);
            AS(&drow[j + 64], s.z);
            AS(&drow[j + 96], s.w);
            // drain THIS wave's stores, then publish row flag
            asm volatile("s_waitcnt vmcnt(0)" ::: "memory");
            if (l == 0) AS(&wflags[bb * 16 + jjg * 4 + rr], (uint32)(t + 1));
        }
    }
}

__global__ __launch_bounds__(256) void rnn_tail_kernel(
    const float* __restrict__ hfin,   // final h in buf 0 (TT even)
    const float* __restrict__ lin_W, const float* __restrict__ lin_b,
    const int* __restrict__ y, float* __restrict__ out)
{
    __shared__ float redf[256];
    __shared__ int   redi[256];
    const int b = threadIdx.x;
    const float* hrow = hfin + (size_t)b * HH;

    float logits[NCLS];
    #pragma unroll
    for (int c = 0; c < NCLS; ++c) {
        float s = lin_b[c];
        const float* wrow = lin_W + (size_t)c * HH;
        for (int k = 0; k < HH; k += 4) {
            float4 hv = *(const float4*)(hrow + k);
            float4 wv = *(const float4*)(wrow + k);
            s += hv.x * wv.x + hv.y * wv.y + hv.z * wv.z + hv.w * wv.w;
        }
        logits[c] = s;
    }
    int am = 0; float m = logits[0];
    #pragma unroll
    for (int c = 1; c < NCLS; ++c) if (logits[c] > m) { m = logits[c]; am = c; } // first-max
    float sum = 0.0f;
    #pragma unroll
    for (int c = 0; c < NCLS; ++c) sum += expf(logits[c] - m);
    const float lse = m + logf(sum);
    const int yy = y[b];
    redf[b] = lse - logits[yy];
    redi[b] = (am == yy) ? 1 : 0;
    __syncthreads();
    for (int s2 = 128; s2 > 0; s2 >>= 1) {
        if (b < s2) { redf[b] += redf[b + s2]; redi[b] += redi[b + s2]; }
        __syncthreads();
    }
    if (b == 0) {
        out[0] = redf[0] / (float)BATCH;  // loss
        out[1] = (float)redi[0];          // correct count
    }
}

extern "C" void kernel_launch(void* const* d_in, const int* in_sizes, int n_in,
                              void* d_out, int out_size, void* d_ws, size_t ws_size,
                              hipStream_t stream) {
    const float* inputs = (const float*)d_in[0];
    const int*   y      = (const int*)  d_in[1];
    const int*   order  = (const int*)  d_in[2];
    const float* W_ih   = (const float*)d_in[3];
    const float* b_ih   = (const float*)d_in[4];
    const float* W_hh   = (const float*)d_in[5];
    const float* b_hh   = (const float*)d_in[6];
    const float* lin_W  = (const float*)d_in[7];
    const float* lin_b  = (const float*)d_in[8];
    float* out = (float*)d_out;

    uint32* wflags = (uint32*)d_ws;
    float*  hbuf   = (float*)((char*)d_ws + 8192);

    hipLaunchKernelGGL(rnn_init_kernel, dim3(4), dim3(256), 0, stream, wflags);

    void* args[] = {(void*)&inputs, (void*)&order, (void*)&W_ih, (void*)&b_ih,
                    (void*)&W_hh, (void*)&b_hh, (void*)&hbuf, (void*)&wflags};
    hipError_t err = hipLaunchCooperativeKernel((void*)rnn_main_kernel,
                                                dim3(NB * NJ), dim3(NT), args, 0, stream);
    if (err != hipSuccess) {
        hipLaunchKernelGGL(rnn_main_kernel, dim3(NB * NJ), dim3(NT), 0, stream,
                           inputs, order, W_ih, b_ih, W_hh, b_hh, hbuf, wflags);
    }

    hipLaunchKernelGGL(rnn_tail_kernel, dim3(1), dim3(256), 0, stream,
                       hbuf, lin_W, lin_b, y, out);
}

// Round 8
// 2729.782 us; speedup vs baseline: 4.7111x; 1.6729x over previous
//
#include <hip/hip_runtime.h>
#include <math.h>

#define BATCH 256
#define TT    784
#define HH    512
#define NCLS  10

#define NB 64          // batch groups
#define NJ 4           // blocks per group; block owns 128 cols
#define MB 4           // batch rows per group
#define HJ 128         // output cols per block
#define NT 512         // threads per block (8 waves, 2/SIMD)

typedef unsigned long long ull;
typedef unsigned int uint32;

#define AL(p)    __hip_atomic_load((p), __ATOMIC_RELAXED, __HIP_MEMORY_SCOPE_AGENT)
#define AS(p, v) __hip_atomic_store((p), (v), __ATOMIC_RELAXED, __HIP_MEMORY_SCOPE_AGENT)

// R0-R7 LESSONS (journal):
//  * VGPR stuck at ~120 across ALL configs incl. 87 KB LDS (1 block/CU) —
//    the "LDS->occupancy->budget" theory is refuted. No scratch signature in
//    FETCH (215 MB = exchange only; contrast R6's 33.7 GB real-spill blowup).
//    Weight residency is NOT the bottleneck; surplus lives in the unified
//    VGPR/AGPR file cheaply. Stop fighting the allocator.
//  * R7 (own-block h routed through hbuf + no barrier C): +1.5 ms. The
//    own-slice LDS path is on the critical chain. Keep it + barrier C.
//  * Real budget: ~9500 cyc/step vs 2048 FMA floor; ~6300 cyc = serial
//    pack/B/reduce/drain/flag/poll/stage chain. THIS version compresses the
//    reduce (all 512 threads, scalar layout, 1 output/thread) and splits
//    publish into 8 parallel per-wave half-row flags.
//
// d_ws layout:
//   [0, 8192)   : wflags uint32[NB][32] — flag[bb][jjg*8 + half*4 + row] >= t
//                 <=> producer jjg's (row, col-half) of h_t is visible
//                 (stored + that wave's vmcnt drained).
//   [8192, ...) : double-buffered h state (2 * B * H f32, agent relaxed).

__global__ __launch_bounds__(256) void rnn_init_kernel(uint32* wflags) {
    const int i = blockIdx.x * blockDim.x + threadIdx.x;
    if (i < NB * 32) AS(&wflags[i], 0u);
}

// Opaque register pin: weights become outputs of a volatile asm — cannot be
// rematerialized or sunk into the loop.
#define PIN(V) asm volatile("" : "+v"((V).x), "+v"((V).y), "+v"((V).z), "+v"((V).w))

__global__ __launch_bounds__(NT)
__attribute__((amdgpu_waves_per_eu(2, 2)))
void rnn_main_kernel(
    const float* __restrict__ inputs, const int* __restrict__ order,
    const float* __restrict__ W_ih, const float* __restrict__ b_ih,
    const float* __restrict__ W_hh, const float* __restrict__ b_hh,
    float* __restrict__ hbuf, uint32* __restrict__ wflags)
{
    __shared__ float hp[MB * HH];            // 8 KB : h tile (canonical col layout)
    __shared__ float pbuf[16 * MB * HJ];     // 32 KB: partials, SCALAR [kk][row][col]
    __shared__ float xall[TT * MB];          // 12.25 KB: inputs[b][order[t]]
    __shared__ float wih_s[HJ];
    __shared__ float bias_s[HJ];

    const int tid   = threadIdx.x;
    const int blk   = blockIdx.x;
    const int bb    = blk & (NB - 1);        // group; members blk=bb+64g -> same XCD under %8
    const int jjg   = blk >> 6;              // producer id 0..3: cols [jjg*128, +128)
    const int jbase = jjg * HJ;
    const int bbase = bb * MB;
    const int j   = tid & 31;                // base col lane: cols {j, j+32, j+64, j+96}
    const int kg  = tid >> 5;                // k-chunk 0..15 (32 k each)
    const int w   = tid >> 6;                // wave: k-window [64w,+64), producer g=w>>1
    const int g   = w >> 1;
    const int l   = tid & 63;
    const int r4  = l >> 4;                  // staging: batch row 0..3
    const int c4  = l & 15;                  // staging: 16B chunk within 64-col window

    // ---- W_hh slice in NAMED registers: 4 cols x 32 k = 32 float4 (128 VGPR)
    const float4* wpa = (const float4*)(W_hh + (size_t)(jbase + j +  0) * HH + kg * 32);
    const float4* wpb = (const float4*)(W_hh + (size_t)(jbase + j + 32) * HH + kg * 32);
    const float4* wpc = (const float4*)(W_hh + (size_t)(jbase + j + 64) * HH + kg * 32);
    const float4* wpd = (const float4*)(W_hh + (size_t)(jbase + j + 96) * HH + kg * 32);
    float4 wa0 = wpa[0], wa1 = wpa[1], wa2 = wpa[2], wa3 = wpa[3];
    float4 wa4 = wpa[4], wa5 = wpa[5], wa6 = wpa[6], wa7 = wpa[7];
    float4 wb0 = wpb[0], wb1 = wpb[1], wb2 = wpb[2], wb3 = wpb[3];
    float4 wb4 = wpb[4], wb5 = wpb[5], wb6 = wpb[6], wb7 = wpb[7];
    float4 wc0 = wpc[0], wc1 = wpc[1], wc2 = wpc[2], wc3 = wpc[3];
    float4 wc4 = wpc[4], wc5 = wpc[5], wc6 = wpc[6], wc7 = wpc[7];
    float4 wd0 = wpd[0], wd1 = wpd[1], wd2 = wpd[2], wd3 = wpd[3];
    float4 wd4 = wpd[4], wd5 = wpd[5], wd6 = wpd[6], wd7 = wpd[7];

    PIN(wa0); PIN(wa1); PIN(wa2); PIN(wa3);
    PIN(wa4); PIN(wa5); PIN(wa6); PIN(wa7);
    PIN(wb0); PIN(wb1); PIN(wb2); PIN(wb3);
    PIN(wb4); PIN(wb5); PIN(wb6); PIN(wb7);
    PIN(wc0); PIN(wc1); PIN(wc2); PIN(wc3);
    PIN(wc4); PIN(wc5); PIN(wc6); PIN(wc7);
    PIN(wd0); PIN(wd1); PIN(wd2); PIN(wd3);
    PIN(wd4); PIN(wd5); PIN(wd6); PIN(wd7);

    if (tid < HJ) {
        wih_s[tid]  = W_ih[jbase + tid];
        bias_s[tid] = b_ih[jbase + tid] + b_hh[jbase + tid];
    }
    for (int idx = tid; idx < TT * MB; idx += NT) {
        const int t = idx >> 2;
        const int b = idx & (MB - 1);
        xall[idx] = inputs[(size_t)(bbase + b) * TT + order[t]];
    }
    ((float4*)hp)[tid] = make_float4(0.f, 0.f, 0.f, 0.f);   // h_0 = 0 (8 KB)
    __syncthreads();

    const float4* hp4 = (const float4*)hp;

    for (int t = 0; t < TT; ++t) {
        const int p = t & 1;

        // ---- per-wave gate + stage: poll the 4 half-row flags covering this
        //      wave's 64-col k-window (contiguous dwords), then load 1 KB
        if (t > 0 && g != jjg) {
            const uint32 tg = (uint32)t;
            const ull* f8 = (const ull*)(wflags + bb * 32 + g * 8 + (w & 1) * 4);
            for (;;) {
                const ull f0 = AL(f8), f1 = AL(f8 + 1);
                if ((uint32)f0 >= tg && (uint32)(f0 >> 32) >= tg &&
                    (uint32)f1 >= tg && (uint32)(f1 >> 32) >= tg) break;
            }
            const ull* src = (const ull*)(hbuf + (size_t)p * BATCH * HH
                                          + (size_t)(bbase + r4) * HH + w * 64 + c4 * 4);
            const ull u0 = AL(src), u1 = AL(src + 1);
            ull* hpu = (ull*)hp;
            const int di = (r4 * HH + w * 64 + c4 * 4) >> 1;
            hpu[di] = u0; hpu[di + 1] = u1;
        }
        // intra-wave LDS RAW: compiler's lgkmcnt covers the hp reads below.

        // ---- partials: 4 rows x 4 cols, k-window 32; h reads are 2-addr broadcasts
        float aa0=0.f,aa1=0.f,aa2=0.f,aa3=0.f;
        float ab0=0.f,ab1=0.f,ab2=0.f,ab3=0.f;
        float ac0=0.f,ac1=0.f,ac2=0.f,ac3=0.f;
        float ad0=0.f,ad1=0.f,ad2=0.f,ad3=0.f;

#define FMA4(ACC, WV, HV) \
        ACC = fmaf(WV.x, HV.x, ACC); ACC = fmaf(WV.y, HV.y, ACC); \
        ACC = fmaf(WV.z, HV.z, ACC); ACC = fmaf(WV.w, HV.w, ACC);
#define ROW(B) { \
        const float4* hr = hp4 + (B)*128 + kg*8; \
        const float4 h0=hr[0],h1=hr[1],h2=hr[2],h3=hr[3]; \
        const float4 h4=hr[4],h5=hr[5],h6=hr[6],h7=hr[7]; \
        FMA4(aa##B, wa0,h0) FMA4(aa##B, wa1,h1) FMA4(aa##B, wa2,h2) FMA4(aa##B, wa3,h3) \
        FMA4(aa##B, wa4,h4) FMA4(aa##B, wa5,h5) FMA4(aa##B, wa6,h6) FMA4(aa##B, wa7,h7) \
        FMA4(ab##B, wb0,h0) FMA4(ab##B, wb1,h1) FMA4(ab##B, wb2,h2) FMA4(ab##B, wb3,h3) \
        FMA4(ab##B, wb4,h4) FMA4(ab##B, wb5,h5) FMA4(ab##B, wb6,h6) FMA4(ab##B, wb7,h7) \
        FMA4(ac##B, wc0,h0) FMA4(ac##B, wc1,h1) FMA4(ac##B, wc2,h2) FMA4(ac##B, wc3,h3) \
        FMA4(ac##B, wc4,h4) FMA4(ac##B, wc5,h5) FMA4(ac##B, wc6,h6) FMA4(ac##B, wc7,h7) \
        FMA4(ad##B, wd0,h0) FMA4(ad##B, wd1,h1) FMA4(ad##B, wd2,h2) FMA4(ad##B, wd3,h3) \
        FMA4(ad##B, wd4,h4) FMA4(ad##B, wd5,h5) FMA4(ad##B, wd6,h6) FMA4(ad##B, wd7,h7) }

        ROW(0) __builtin_amdgcn_sched_barrier(0);
        ROW(1) __builtin_amdgcn_sched_barrier(0);
        ROW(2) __builtin_amdgcn_sched_barrier(0);
        ROW(3) __builtin_amdgcn_sched_barrier(0);
#undef ROW
#undef FMA4

        // pack: SCALAR layout pbuf[kg*512 + row*128 + col]; per store-instr the
        // 64 lanes write 2x32 consecutive floats -> conflict-free
#define PK(B) \
        pbuf[kg*512 + (B)*128 + j     ] = aa##B; \
        pbuf[kg*512 + (B)*128 + j + 32] = ab##B; \
        pbuf[kg*512 + (B)*128 + j + 64] = ac##B; \
        pbuf[kg*512 + (B)*128 + j + 96] = ad##B;
        PK(0) PK(1) PK(2) PK(3)
#undef PK
        __syncthreads();                 // B: all partials ready

        // ---- reduce: ALL 512 threads, one output each: row=tid>>7, col=tid&127
        //      (addr identity: row*128+col == tid). 16 stride-1 scalar reads
        //      (2-way bank alias = free), 1 tanh, 1 coalesced store/lane.
        //      Wave w covers (row=w>>1, half=w&1) -> publishes its own flag.
        {
            const int row = tid >> 7;
            const int col = tid & 127;
            float s = pbuf[tid];
            #pragma unroll
            for (int kk = 1; kk < 16; ++kk) s += pbuf[kk * 512 + tid];
            const float xv = xall[t * MB + row];
            s = tanhf(s + xv * wih_s[col] + bias_s[col]);
            AS(&hbuf[(size_t)(p ^ 1) * BATCH * HH
                     + (size_t)(bbase + row) * HH + jbase + col], s);
            // own-slice shortcut for own-block consumer waves next step
            hp[row * HH + jbase + col] = s;
            // drain THIS wave's hbuf stores, then publish its half-row flag
            asm volatile("s_waitcnt vmcnt(0)" ::: "memory");
            if (l == 0) AS(&wflags[bb * 32 + jjg * 8 + (w & 1) * 4 + (w >> 1)],
                           (uint32)(t + 1));
        }
        __syncthreads();                 // C: pbuf WAR + own-slice visible
    }
}

__global__ __launch_bounds__(256) void rnn_tail_kernel(
    const float* __restrict__ hfin,   // final h in buf 0 (TT even)
    const float* __restrict__ lin_W, const float* __restrict__ lin_b,
    const int* __restrict__ y, float* __restrict__ out)
{
    __shared__ float redf[256];
    __shared__ int   redi[256];
    const int b = threadIdx.x;
    const float* hrow = hfin + (size_t)b * HH;

    float logits[NCLS];
    #pragma unroll
    for (int c = 0; c < NCLS; ++c) {
        float s = lin_b[c];
        const float* wrow = lin_W + (size_t)c * HH;
        for (int k = 0; k < HH; k += 4) {
            float4 hv = *(const float4*)(hrow + k);
            float4 wv = *(const float4*)(wrow + k);
            s += hv.x * wv.x + hv.y * wv.y + hv.z * wv.z + hv.w * wv.w;
        }
        logits[c] = s;
    }
    int am = 0; float m = logits[0];
    #pragma unroll
    for (int c = 1; c < NCLS; ++c) if (logits[c] > m) { m = logits[c]; am = c; } // first-max
    float sum = 0.0f;
    #pragma unroll
    for (int c = 0; c < NCLS; ++c) sum += expf(logits[c] - m);
    const float lse = m + logf(sum);
    const int yy = y[b];
    redf[b] = lse - logits[yy];
    redi[b] = (am == yy) ? 1 : 0;
    __syncthreads();
    for (int s2 = 128; s2 > 0; s2 >>= 1) {
        if (b < s2) { redf[b] += redf[b + s2]; redi[b] += redi[b + s2]; }
        __syncthreads();
    }
    if (b == 0) {
        out[0] = redf[0] / (float)BATCH;  // loss
        out[1] = (float)redi[0];          // correct count
    }
}

extern "C" void kernel_launch(void* const* d_in, const int* in_sizes, int n_in,
                              void* d_out, int out_size, void* d_ws, size_t ws_size,
                              hipStream_t stream) {
    const float* inputs = (const float*)d_in[0];
    const int*   y      = (const int*)  d_in[1];
    const int*   order  = (const int*)  d_in[2];
    const float* W_ih   = (const float*)d_in[3];
    const float* b_ih   = (const float*)d_in[4];
    const float* W_hh   = (const float*)d_in[5];
    const float* b_hh   = (const float*)d_in[6];
    const float* lin_W  = (const float*)d_in[7];
    const float* lin_b  = (const float*)d_in[8];
    float* out = (float*)d_out;

    uint32* wflags = (uint32*)d_ws;
    float*  hbuf   = (float*)((char*)d_ws + 8192);

    hipLaunchKernelGGL(rnn_init_kernel, dim3(8), dim3(256), 0, stream, wflags);

    void* args[] = {(void*)&inputs, (void*)&order, (void*)&W_ih, (void*)&b_ih,
                    (void*)&W_hh, (void*)&b_hh, (void*)&hbuf, (void*)&wflags};
    hipError_t err = hipLaunchCooperativeKernel((void*)rnn_main_kernel,
                                                dim3(NB * NJ), dim3(NT), args, 0, stream);
    if (err != hipSuccess) {
        hipLaunchKernelGGL(rnn_main_kernel, dim3(NB * NJ), dim3(NT), 0, stream,
                           inputs, order, W_ih, b_ih, W_hh, b_hh, hbuf, wflags);
    }

    hipLaunchKernelGGL(rnn_tail_kernel, dim3(1), dim3(256), 0, stream,
                       hbuf, lin_W, lin_b, y, out);
}